// Round 6
// baseline (142.717 us; speedup 1.0000x reference)
//
#include <hip/hip_runtime.h>
#include <math.h>

// Problem constants
#define DIM   256
#define NST   256
#define LSEQ  512
#define BAT   2
#define DTSZ  64
#define PCOLS 576
#define NROWS 1024
#define NPROJ 288            // blocks that carry proj work (32 mt x 9 roles)
#define GOIDX NPROJ          // go-flag cell index
#define SENT  0x5AFE6A7Bu    // sentinel; not a repeated-byte poison pattern

typedef float    f32x4 __attribute__((ext_vector_type(4)));
typedef unsigned u32x4 __attribute__((ext_vector_type(4)));

constexpr float LOG2E = 1.4426950408889634f;

__device__ __forceinline__ float fexp2(float v) {
#if __has_builtin(__builtin_amdgcn_exp2f)
    return __builtin_amdgcn_exp2f(v);
#else
    return exp2f(v);
#endif
}

__device__ __forceinline__ float softplusf(float v) {
    return (v > 20.f) ? v : log1pf(__expf(v));
}

// LDS-only barrier: waits lgkmcnt(0) but leaves global (vmcnt) loads in flight.
__device__ __forceinline__ void barrier_lds_only() {
    __builtin_amdgcn_s_waitcnt(0xC07F);   // vmcnt=63, expcnt=7, lgkmcnt=0
    __builtin_amdgcn_s_barrier();
}

// Pack (beta, gamma) as bf16x2 in one dword: beta lo16, gamma hi16. RNE.
__device__ __forceinline__ unsigned pack_bg(float be, float ga) {
    unsigned ub = __float_as_uint(be);
    unsigned ug = __float_as_uint(ga);
    ub = (ub + 0x7fffu + ((ub >> 16) & 1u)) >> 16;
    ug = (ug + 0x7fffu + ((ug >> 16) & 1u)) & 0xffff0000u;
    return ub | ug;
}

// fp32 -> bf16 (RNE) as u16.
__device__ __forceinline__ unsigned short rne16(float f) {
    unsigned u = __float_as_uint(f);
    return (unsigned short)((u + 0x7fffu + ((u >> 16) & 1u)) >> 16);
}

// v_cvt_pk_bf16_f32: two fp32 -> packed bf16x2 (lo = src0, hi = src1), 1 instr.
__device__ __forceinline__ unsigned cvtpk(float lo, float hi) {
    unsigned r;
    asm("v_cvt_pk_bf16_f32 %0, %1, %2" : "=v"(r) : "v"(lo), "v"(hi));
    return r;
}

// MFMA via inline asm. D = A(16x32 bf16) * B(32x16 bf16) + C.
// A: row=lane&15, k=(lane>>4)*8+i.  B: col=lane&15, k=(lane>>4)*8+i.
// C/D: col=lane&15, row=(lane>>4)*4+r.   (verified R4 in-harness)
__device__ __forceinline__ f32x4 mfma16(u32x4 a, u32x4 b, f32x4 c) {
    asm("v_mfma_f32_16x16x32_bf16 %0, %1, %2, %0" : "+v"(c) : "v"(a), "v"(b));
    return c;
}

// ---------------- fused: phase A = R4 proj_mfma (verbatim, blocks 0..287),
// software grid barrier (flags in poisoned ws; sentinel protocol),
// phase B = R4 scan1p with fused dt prologue (verbatim, all 512 blocks).
// Residency: LDS 39168 B/block -> <=4 blocks/CU capacity (1024 >= 512 grid)
// so all blocks are co-resident and the spin barrier cannot deadlock.
__global__ __launch_bounds__(256, 2) void fused(
    const float* __restrict__ x, const float* __restrict__ W_in,
    const float* __restrict__ W_dt, const float* __restrict__ b_dt,
    const float* __restrict__ alpha_log, const float* __restrict__ delta,
    unsigned* __restrict__ betgam,     // [NROWS, NST] bf16x2
    float* __restrict__ draw,          // [NROWS, DTSZ] fp32 dt_raw
    unsigned* flags,                   // [NPROJ+1] barrier cells (poisoned each iter)
    float* __restrict__ out)           // [NROWS, DIM]
{
    __shared__ union ShMem {
        unsigned short Bt[64][264];    // 33792 B  (phase A)
        struct {                       // 39168 B  (phase B)
            float part[32][NST];
            float dts[LSEQ], dxs[LSEQ], xcol[LSEQ];
            float wdt[DTSZ];
        } s;
    } U;

    const int tid  = threadIdx.x;
    const int lane = tid & 63;
    const int bid  = blockIdx.x;

    // ================= phase A: proj (R4-verified body) =================
    if (bid < NPROJ) {
        const int mt   = bid / 9;
        const int role = bid % 9;
        const int base0 = (role < 8) ? (64  + 32 * role) : 0;
        const int base1 = (role < 8) ? (320 + 32 * role) : 32;
        {
            const int cl = tid & 31;          // col within strip
            const int kq = tid >> 5;          // 0..7
            #pragma unroll 8
            for (int p = 0; p < 32; ++p) {
                const int k = p * 8 + kq;
                U.Bt[cl][k]      = rne16(W_in[k * PCOLS + base0 + cl]);
                U.Bt[32 + cl][k] = rne16(W_in[k * PCOLS + base1 + cl]);
            }
        }
        __syncthreads();

        const int w    = tid >> 6;
        const int wm   = w >> 1, wn = w & 1;
        const int row  = mt * 32 + wm * 16 + (lane & 15);
        const int koff = (lane >> 4) * 8;
        const float* xp = x + row * DIM + koff;
        const unsigned short* bp1 = &U.Bt[16 * wn + (lane & 15)][koff];
        const unsigned short* bp2 = &U.Bt[32 + 16 * wn + (lane & 15)][koff];

        f32x4 acc1 = {0.f, 0.f, 0.f, 0.f};
        f32x4 acc2 = {0.f, 0.f, 0.f, 0.f};
        #pragma unroll
        for (int kk = 0; kk < 8; ++kk) {     // K = 8 x 32
            const float4 xa = *(const float4*)(xp + kk * 32);
            const float4 xb = *(const float4*)(xp + kk * 32 + 4);
            u32x4 a;
            a.x = cvtpk(xa.x, xa.y);
            a.y = cvtpk(xa.z, xa.w);
            a.z = cvtpk(xb.x, xb.y);
            a.w = cvtpk(xb.z, xb.w);
            const u32x4 b1 = *(const u32x4*)(bp1 + kk * 32);
            const u32x4 b2 = *(const u32x4*)(bp2 + kk * 32);
            acc1 = mfma16(a, b1, acc1);
            acc2 = mfma16(a, b2, acc2);
        }

        const int rowbase = mt * 32 + wm * 16 + (lane >> 4) * 4;
        if (role < 8) {
            const int n = 32 * role + 16 * wn + (lane & 15);
            #pragma unroll
            for (int r = 0; r < 4; ++r)
                betgam[(rowbase + r) * NST + n] = pack_bg(acc1[r], acc2[r]);
        } else {
            const int c1 = 16 * wn + (lane & 15);
            #pragma unroll
            for (int r = 0; r < 4; ++r) {
                draw[(rowbase + r) * DTSZ + c1]      = acc1[r];
                draw[(rowbase + r) * DTSZ + 32 + c1] = acc2[r];
            }
        }
        // All Bt reads done + all global stores drained (syncthreads waits
        // vmcnt(0) per wave) before LDS reuse and before signaling.
        __syncthreads();
        __builtin_amdgcn_fence(__ATOMIC_RELEASE, "agent");   // L2 writeback
        if (tid == 0) atomicExch(&flags[bid], SENT);
    }

    // ========== phase-B geometry + phase-A-independent staging ==========
    const int n    = tid;
    const int xcd  = bid & 7;               // XCD swizzle (R10-verified)
    const int slot = bid >> 3;              // 0..63
    const int b    = xcd >> 2;
    const int d    = slot * 4 + (xcd & 3);
    const int rb   = b * LSEQ;

    if (n < DTSZ) U.s.wdt[n] = W_dt[n * DIM + d];
    #pragma unroll
    for (int it = 0; it < 2; ++it) {
        const int l = n + it * 256;
        U.s.xcol[l] = x[(rb + l) * DIM + d];
    }
    const float aln = -__expf(alpha_log[d * NST + n]) * LOG2E;
    const float dv  = delta[d];
    const float bdv = b_dt[d];

    // ===================== software grid barrier =======================
    if (bid == 511) {
        for (int i = tid; i < NPROJ; i += 256)
            while (atomicAdd(&flags[i], 0u) != SENT)
                __builtin_amdgcn_s_sleep(8);
        __syncthreads();                    // all 288 producer flags seen
        if (tid == 0) atomicExch(&flags[GOIDX], SENT);
    } else {
        if (tid == 0)
            while (atomicAdd(&flags[GOIDX], 0u) != SENT)
                __builtin_amdgcn_s_sleep(8);
        __syncthreads();
    }
    __builtin_amdgcn_fence(__ATOMIC_ACQUIRE, "agent");       // inv stale caches
    __syncthreads();                        // also covers wdt/xcol LDS staging

    // ============== phase B: scan (R4-verified body) ====================
    // Fused dt GEMM: dts[l] = softplus(draw[rb+l,:] . wdt + b_dt[d])
    #pragma unroll
    for (int it = 0; it < 2; ++it) {
        const int l = n + it * 256;
        const float4* dr = (const float4*)&draw[(rb + l) * DTSZ];
        float acc = bdv;
        #pragma unroll
        for (int c = 0; c < 16; ++c) {
            const float4 v  = dr[c];
            const float4 wv = *(const float4*)&U.s.wdt[c * 4];
            acc = fmaf(v.x, wv.x, acc);
            acc = fmaf(v.y, wv.y, acc);
            acc = fmaf(v.z, wv.z, acc);
            acc = fmaf(v.w, wv.w, acc);
        }
        const float sp = softplusf(acc);
        U.s.dts[l] = sp;
        U.s.dxs[l] = sp * U.s.xcol[l];
    }
    __syncthreads();                        // dts/dxs ready

    float s = 0.f;
    unsigned bg[8][8];                      // 8-slot rotation, 6 windows ahead
    #pragma unroll
    for (int pw = 0; pw < 6; ++pw) {
        #pragma unroll
        for (int t = 0; t < 8; ++t)
            bg[pw][t] = betgam[(rb + pw * 8 + t) * NST + n];
    }

    #pragma unroll 8
    for (int w = 0; w < 64; ++w) {
        const int cur = w & 7;
        const int pf  = (w + 6) & 7;
        if (w + 6 < 64) {                   // issue window w+6 while computing w
            #pragma unroll
            for (int t = 0; t < 8; ++t)
                bg[pf][t] = betgam[(rb + (w + 6) * 8 + t) * NST + n];
        }
        float4 dta = *(const float4*)&U.s.dts[w * 8];
        float4 dtb = *(const float4*)&U.s.dts[w * 8 + 4];
        float4 dxa = *(const float4*)&U.s.dxs[w * 8];
        float4 dxb = *(const float4*)&U.s.dxs[w * 8 + 4];
        const float dtw[8] = {dta.x, dta.y, dta.z, dta.w, dtb.x, dtb.y, dtb.z, dtb.w};
        const float dxw[8] = {dxa.x, dxa.y, dxa.z, dxa.w, dxb.x, dxb.y, dxb.z, dxb.w};

        const int prow = (w & 3) * 8;
        #pragma unroll
        for (int t = 0; t < 8; ++t) {
            const unsigned u = bg[cur][t];
            const float be = __uint_as_float(u << 16);
            const float ga = __uint_as_float(u & 0xffff0000u);
            float a = fexp2(dtw[t] * aln);
            s = fmaf(a, s, dxw[t] * be);
            U.s.part[prow + t][n] = s * ga;  // 2-way bank alias: free
        }

        if ((w & 3) == 3) {                 // every 32 steps: reduce 32 rows x 256
            barrier_lds_only();
            const int trow = n >> 3, seg = n & 7;
            float sum = 0.f;
            #pragma unroll
            for (int k = 0; k < 32; ++k)
                sum += U.s.part[trow][seg * 32 + ((k + n) & 31)];  // 0-conflict
            sum += __shfl_xor(sum, 1);
            sum += __shfl_xor(sum, 2);
            sum += __shfl_xor(sum, 4);
            if (seg == 0) {
                const int l = (w >> 2) * 32 + trow;
                out[(rb + l) * DIM + d] = sum + U.s.xcol[l] * dv;
            }
            barrier_lds_only();             // WAR before next window's writes
        }
    }
}

extern "C" void kernel_launch(void* const* d_in, const int* in_sizes, int n_in,
                              void* d_out, int out_size, void* d_ws, size_t ws_size,
                              hipStream_t stream) {
    const float* x         = (const float*)d_in[0];
    const float* W_in      = (const float*)d_in[1];
    const float* W_dt      = (const float*)d_in[2];
    const float* b_dt      = (const float*)d_in[3];
    const float* alpha_log = (const float*)d_in[4];
    const float* delta     = (const float*)d_in[5];
    float* out = (float*)d_out;

    // Workspace: betgam 1MB | draw 256KB | flags (NPROJ+1) u32
    unsigned* betgam = (unsigned*)d_ws;
    float* draw      = (float*)(betgam + NROWS * NST);
    unsigned* flags  = (unsigned*)(draw + NROWS * DTSZ);

    fused<<<512, 256, 0, stream>>>(x, W_in, W_dt, b_dt, alpha_log, delta,
                                   betgam, draw, flags, out);
}

// Round 7
// 107.077 us; speedup vs baseline: 1.3329x; 1.3329x over previous
//
#include <hip/hip_runtime.h>
#include <math.h>

// Problem constants
#define DIM   256
#define NST   256
#define LSEQ  512
#define BAT   2
#define DTSZ  64
#define PCOLS 576
#define NROWS 1024

typedef float    f32x4 __attribute__((ext_vector_type(4)));
typedef unsigned u32x4 __attribute__((ext_vector_type(4)));

constexpr float LOG2E = 1.4426950408889634f;

__device__ __forceinline__ float fexp2(float v) {
#if __has_builtin(__builtin_amdgcn_exp2f)
    return __builtin_amdgcn_exp2f(v);
#else
    return exp2f(v);
#endif
}

__device__ __forceinline__ float softplusf(float v) {
    return (v > 20.f) ? v : log1pf(__expf(v));
}

// LDS-only barrier: waits lgkmcnt(0) but leaves global (vmcnt) loads in flight.
__device__ __forceinline__ void barrier_lds_only() {
    __builtin_amdgcn_s_waitcnt(0xC07F);   // vmcnt=63, expcnt=7, lgkmcnt=0
    __builtin_amdgcn_s_barrier();
}

// Pack (beta, gamma) as bf16x2 in one dword: beta lo16, gamma hi16. RNE.
__device__ __forceinline__ unsigned pack_bg(float be, float ga) {
    unsigned ub = __float_as_uint(be);
    unsigned ug = __float_as_uint(ga);
    ub = (ub + 0x7fffu + ((ub >> 16) & 1u)) >> 16;
    ug = (ug + 0x7fffu + ((ug >> 16) & 1u)) & 0xffff0000u;
    return ub | ug;
}

// fp32 -> bf16 (RNE) as u16.
__device__ __forceinline__ unsigned short rne16(float f) {
    unsigned u = __float_as_uint(f);
    return (unsigned short)((u + 0x7fffu + ((u >> 16) & 1u)) >> 16);
}

// v_cvt_pk_bf16_f32: two fp32 -> packed bf16x2 (lo = src0, hi = src1), 1 instr.
__device__ __forceinline__ unsigned cvtpk(float lo, float hi) {
    unsigned r;
    asm("v_cvt_pk_bf16_f32 %0, %1, %2" : "=v"(r) : "v"(lo), "v"(hi));
    return r;
}

// MFMA via inline asm. D = A(16x32 bf16) * B(32x16 bf16) + C.
// A: row=lane&15, k=(lane>>4)*8+i.  B: col=lane&15, k=(lane>>4)*8+i.
// C/D: col=lane&15, row=(lane>>4)*4+r.   (verified R4 in-harness)
__device__ __forceinline__ f32x4 mfma16(u32x4 a, u32x4 b, f32x4 c) {
    asm("v_mfma_f32_16x16x32_bf16 %0, %1, %2, %0" : "+v"(c) : "v"(a), "v"(b));
    return c;
}

// ---------------- proj_mfma: x@W_in via bf16 MFMA (R4-verified core).
// Grid 288 = 32 row-tiles x 9 roles. Roles 0-7: matched (beta,gamma) strip
// pairs -> betgam packed locally. Role 8: dt_raw cols 0..63 -> draw[].
// NEW this round: betgam stored as ROW-QUADS: betgam4[(row>>2)*NST + n] is a
// u32x4 whose element r is packed (beta,gamma) for row 4*(row>>2)+r, state n.
// Writer holds exactly rows rowbase..rowbase+3 (rowbase%4==0) per lane ->
// the 4 dword stores collapse to ONE dwordx4 store.
__global__ __launch_bounds__(256, 2) void proj_mfma(
    const float* __restrict__ x, const float* __restrict__ W_in,
    u32x4* __restrict__ betgam4,       // [NROWS/4, NST] row-quads
    float* __restrict__ draw)          // [NROWS, DTSZ] fp32 dt_raw
{
    __shared__ unsigned short Bt[64][264];   // 33792 B
    const int tid  = threadIdx.x;
    const int lane = tid & 63;
    const int mt   = blockIdx.x / 9;
    const int role = blockIdx.x % 9;

    // ---- stage B: 2 strips of 32 cols, transposed into LDS as [col][k]
    const int base0 = (role < 8) ? (64  + 32 * role) : 0;
    const int base1 = (role < 8) ? (320 + 32 * role) : 32;
    {
        const int cl = tid & 31;          // col within strip
        const int kq = tid >> 5;          // 0..7
        #pragma unroll 8
        for (int p = 0; p < 32; ++p) {
            const int k = p * 8 + kq;
            Bt[cl][k]      = rne16(W_in[k * PCOLS + base0 + cl]);
            Bt[32 + cl][k] = rne16(W_in[k * PCOLS + base1 + cl]);
        }
    }
    __syncthreads();

    const int w    = tid >> 6;
    const int wm   = w >> 1, wn = w & 1;
    const int row  = mt * 32 + wm * 16 + (lane & 15);
    const int koff = (lane >> 4) * 8;
    const float* xp = x + row * DIM + koff;
    const unsigned short* bp1 = &Bt[16 * wn + (lane & 15)][koff];
    const unsigned short* bp2 = &Bt[32 + 16 * wn + (lane & 15)][koff];

    f32x4 acc1 = {0.f, 0.f, 0.f, 0.f};
    f32x4 acc2 = {0.f, 0.f, 0.f, 0.f};
    #pragma unroll
    for (int kk = 0; kk < 8; ++kk) {     // K = 8 x 32
        const float4 xa = *(const float4*)(xp + kk * 32);
        const float4 xb = *(const float4*)(xp + kk * 32 + 4);
        u32x4 a;
        a.x = cvtpk(xa.x, xa.y);
        a.y = cvtpk(xa.z, xa.w);
        a.z = cvtpk(xb.x, xb.y);
        a.w = cvtpk(xb.z, xb.w);
        const u32x4 b1 = *(const u32x4*)(bp1 + kk * 32);
        const u32x4 b2 = *(const u32x4*)(bp2 + kk * 32);
        acc1 = mfma16(a, b1, acc1);
        acc2 = mfma16(a, b2, acc2);
    }

    const int rowbase = mt * 32 + wm * 16 + (lane >> 4) * 4;   // %4 == 0
    if (role < 8) {
        const int n = 32 * role + 16 * wn + (lane & 15);
        u32x4 st;
        st.x = pack_bg(acc1[0], acc2[0]);    // row rowbase+0
        st.y = pack_bg(acc1[1], acc2[1]);    // row rowbase+1
        st.z = pack_bg(acc1[2], acc2[2]);    // row rowbase+2
        st.w = pack_bg(acc1[3], acc2[3]);    // row rowbase+3
        betgam4[(rowbase >> 2) * NST + n] = st;
    } else {
        const int c1 = 16 * wn + (lane & 15);
        #pragma unroll
        for (int r = 0; r < 4; ++r) {
            draw[(rowbase + r) * DTSZ + c1]      = acc1[r];
            draw[(rowbase + r) * DTSZ + 32 + c1] = acc2[r];
        }
    }
}

// ---------------- scan1p: R4 skeleton (measured 44.5us) with
// (a) betgam read as row-quads: 2 dwordx4 loads/window instead of 8 dword
//     loads (wave reads 1KB contiguous; ~-1000 instr/thread incl addr math);
// (b) bg prefetch hoisted ABOVE the dt prologue behind an lgkm-only barrier
//     so the prologue's ~250 instr cover the initial load latency.
__global__ __launch_bounds__(256, 2) void scan1p(
    const float* __restrict__ x,            // [NROWS, DIM]
    const float* __restrict__ alpha_log,    // [DIM, NST]
    const float* __restrict__ delta,        // [DIM]
    const u32x4* __restrict__ betgam4,      // [NROWS/4, NST] row-quads
    const float* __restrict__ draw,         // [NROWS, DTSZ]
    const float* __restrict__ W_dt,         // [DTSZ, DIM]
    const float* __restrict__ b_dt,         // [DIM]
    float* __restrict__ out)                // [NROWS, DIM]
{
    __shared__ float part[32][NST];         // 32 KB
    __shared__ float dts[LSEQ], dxs[LSEQ], xcol[LSEQ];   // 3 x 2 KB
    __shared__ float wdt[DTSZ];             // 256 B
    const int n = threadIdx.x;
    // XCD swizzle (R10-verified): XCDs 0-3 -> b=0, 4-7 -> b=1.
    const int xcd  = blockIdx.x & 7;
    const int slot = blockIdx.x >> 3;       // 0..63
    const int b = xcd >> 2;
    const int d = slot * 4 + (xcd & 3);
    const int rb  = b * LSEQ;
    const int rbq = rb >> 2;                // quad-row base (= b*128)

    if (n < DTSZ) wdt[n] = W_dt[n * DIM + d];
    #pragma unroll
    for (int it = 0; it < 2; ++it) {
        const int l = n + it * 256;
        xcol[l] = x[(rb + l) * DIM + d];
    }
    const float aln = -__expf(alpha_log[d * NST + n]) * LOG2E;
    const float dv  = delta[d];
    const float bdv = b_dt[d];

    // Issue the 6-window betgam prefetch NOW (12 dwordx4 loads); they stay
    // in flight through the dt prologue below.
    u32x4 bg[8][2];                         // 8-slot rotation of row-quads
    #pragma unroll
    for (int pw = 0; pw < 6; ++pw) {
        #pragma unroll
        for (int h = 0; h < 2; ++h)
            bg[pw][h] = betgam4[(rbq + pw * 2 + h) * NST + n];
    }

    barrier_lds_only();                     // wdt/xcol visible; vmcnt untouched

    // Fused dt GEMM: dts[l] = softplus(draw[rb+l,:] . wdt + b_dt[d])
    #pragma unroll
    for (int it = 0; it < 2; ++it) {
        const int l = n + it * 256;
        const float4* dr = (const float4*)&draw[(rb + l) * DTSZ];
        float acc = bdv;
        #pragma unroll
        for (int c = 0; c < 16; ++c) {
            const float4 v  = dr[c];
            const float4 wv = *(const float4*)&wdt[c * 4];
            acc = fmaf(v.x, wv.x, acc);
            acc = fmaf(v.y, wv.y, acc);
            acc = fmaf(v.z, wv.z, acc);
            acc = fmaf(v.w, wv.w, acc);
        }
        const float sp = softplusf(acc);
        dts[l] = sp;
        dxs[l] = sp * xcol[l];
    }
    __syncthreads();                        // dts/dxs ready

    float s = 0.f;
    #pragma unroll 8
    for (int w = 0; w < 64; ++w) {
        const int cur = w & 7;              // static under unroll-8
        const int pf  = (w + 6) & 7;
        if (w + 6 < 64) {                   // issue window w+6 while computing w
            bg[pf][0] = betgam4[(rbq + (w + 6) * 2)     * NST + n];
            bg[pf][1] = betgam4[(rbq + (w + 6) * 2 + 1) * NST + n];
        }
        float4 dta = *(const float4*)&dts[w * 8];
        float4 dtb = *(const float4*)&dts[w * 8 + 4];
        float4 dxa = *(const float4*)&dxs[w * 8];
        float4 dxb = *(const float4*)&dxs[w * 8 + 4];
        const float dtw[8] = {dta.x, dta.y, dta.z, dta.w, dtb.x, dtb.y, dtb.z, dtb.w};
        const float dxw[8] = {dxa.x, dxa.y, dxa.z, dxa.w, dxb.x, dxb.y, dxb.z, dxb.w};

        const int prow = (w & 3) * 8;
        #pragma unroll
        for (int t = 0; t < 8; ++t) {       // t static: bg[cur][t>>2][t&3] const-indexed
            const unsigned u = bg[cur][t >> 2][t & 3];
            const float be = __uint_as_float(u << 16);
            const float ga = __uint_as_float(u & 0xffff0000u);
            float a = fexp2(dtw[t] * aln);
            s = fmaf(a, s, dxw[t] * be);
            part[prow + t][n] = s * ga;     // 2-way bank alias: free
        }

        if ((w & 3) == 3) {                 // every 32 steps: reduce 32 rows x 256
            barrier_lds_only();
            const int trow = n >> 3, seg = n & 7;
            float sum = 0.f;
            #pragma unroll
            for (int k = 0; k < 32; ++k)
                sum += part[trow][seg * 32 + ((k + n) & 31)];   // measured 0-conflict
            sum += __shfl_xor(sum, 1);
            sum += __shfl_xor(sum, 2);
            sum += __shfl_xor(sum, 4);
            if (seg == 0) {
                const int l = (w >> 2) * 32 + trow;
                out[(rb + l) * DIM + d] = sum + xcol[l] * dv;
            }
            barrier_lds_only();             // WAR before next window's writes
        }
    }
}

extern "C" void kernel_launch(void* const* d_in, const int* in_sizes, int n_in,
                              void* d_out, int out_size, void* d_ws, size_t ws_size,
                              hipStream_t stream) {
    const float* x         = (const float*)d_in[0];
    const float* W_in      = (const float*)d_in[1];
    const float* W_dt      = (const float*)d_in[2];
    const float* b_dt      = (const float*)d_in[3];
    const float* alpha_log = (const float*)d_in[4];
    const float* delta     = (const float*)d_in[5];
    float* out = (float*)d_out;

    // Workspace: betgam4 1MB | draw 256KB
    u32x4* betgam4 = (u32x4*)d_ws;
    float* draw    = (float*)(betgam4 + (NROWS / 4) * NST);

    proj_mfma<<<32 * 9, 256, 0, stream>>>(x, W_in, betgam4, draw);
    scan1p<<<BAT * DIM, 256, 0, stream>>>(x, alpha_log, delta, betgam4,
                                          draw, W_dt, b_dt, out);
}

// Round 8
// 106.295 us; speedup vs baseline: 1.3426x; 1.0074x over previous
//
#include <hip/hip_runtime.h>
#include <math.h>

// Problem constants
#define DIM   256
#define NST   256
#define LSEQ  512
#define BAT   2
#define DTSZ  64
#define PCOLS 576
#define NROWS 1024

typedef float    f32x4 __attribute__((ext_vector_type(4)));
typedef unsigned u32x4 __attribute__((ext_vector_type(4)));

constexpr float LOG2E = 1.4426950408889634f;

__device__ __forceinline__ float fexp2(float v) {
#if __has_builtin(__builtin_amdgcn_exp2f)
    return __builtin_amdgcn_exp2f(v);
#else
    return exp2f(v);
#endif
}

__device__ __forceinline__ float softplusf(float v) {
    return (v > 20.f) ? v : log1pf(__expf(v));
}

// LDS-only barrier: waits lgkmcnt(0) but leaves global (vmcnt) loads in flight.
__device__ __forceinline__ void barrier_lds_only() {
    __builtin_amdgcn_s_waitcnt(0xC07F);   // vmcnt=63, expcnt=7, lgkmcnt=0
    __builtin_amdgcn_s_barrier();
}

// Pack (beta, gamma) as bf16x2 in one dword: beta lo16, gamma hi16. RNE.
__device__ __forceinline__ unsigned pack_bg(float be, float ga) {
    unsigned ub = __float_as_uint(be);
    unsigned ug = __float_as_uint(ga);
    ub = (ub + 0x7fffu + ((ub >> 16) & 1u)) >> 16;
    ug = (ug + 0x7fffu + ((ug >> 16) & 1u)) & 0xffff0000u;
    return ub | ug;
}

// fp32 -> bf16 (RNE) as u16.
__device__ __forceinline__ unsigned short rne16(float f) {
    unsigned u = __float_as_uint(f);
    return (unsigned short)((u + 0x7fffu + ((u >> 16) & 1u)) >> 16);
}

// v_cvt_pk_bf16_f32: two fp32 -> packed bf16x2 (lo = src0, hi = src1), 1 instr.
__device__ __forceinline__ unsigned cvtpk(float lo, float hi) {
    unsigned r;
    asm("v_cvt_pk_bf16_f32 %0, %1, %2" : "=v"(r) : "v"(lo), "v"(hi));
    return r;
}

// MFMA via inline asm. D = A(16x32 bf16) * B(32x16 bf16) + C.
// A: row=lane&15, k=(lane>>4)*8+i.  B: col=lane&15, k=(lane>>4)*8+i.
// C/D: col=lane&15, row=(lane>>4)*4+r.   (verified R4 in-harness)
__device__ __forceinline__ f32x4 mfma16(u32x4 a, u32x4 b, f32x4 c) {
    asm("v_mfma_f32_16x16x32_bf16 %0, %1, %2, %0" : "+v"(c) : "v"(a), "v"(b));
    return c;
}

// ---------------- proj_mfma: x@W_in via bf16 MFMA (R4-verified core, R7
// quad-store). This round: W_in stage uses float2 loads (64 -> 32 global
// loads/thread, same bytes/coverage).
__global__ __launch_bounds__(256, 2) void proj_mfma(
    const float* __restrict__ x, const float* __restrict__ W_in,
    u32x4* __restrict__ betgam4,       // [NROWS/4, NST] row-quads
    float* __restrict__ draw)          // [NROWS, DTSZ] fp32 dt_raw
{
    __shared__ unsigned short Bt[64][264];   // 33792 B
    const int tid  = threadIdx.x;
    const int lane = tid & 63;
    const int mt   = blockIdx.x / 9;
    const int role = blockIdx.x % 9;

    // ---- stage B: 2 strips of 32 cols, transposed into LDS as [col][k].
    // float2 along cols: thread covers col-pair 2*cs..2*cs+1, k = p*16+kq.
    const int base0 = (role < 8) ? (64  + 32 * role) : 0;
    const int base1 = (role < 8) ? (320 + 32 * role) : 32;
    {
        const int cs = tid & 15;          // col-pair index (0..15)
        const int kq = tid >> 4;          // 0..15
        #pragma unroll 8
        for (int p = 0; p < 16; ++p) {
            const int k = p * 16 + kq;
            const float2 v0 = *(const float2*)&W_in[k * PCOLS + base0 + 2 * cs];
            const float2 v1 = *(const float2*)&W_in[k * PCOLS + base1 + 2 * cs];
            Bt[2 * cs][k]          = rne16(v0.x);
            Bt[2 * cs + 1][k]      = rne16(v0.y);
            Bt[32 + 2 * cs][k]     = rne16(v1.x);
            Bt[32 + 2 * cs + 1][k] = rne16(v1.y);
        }
    }
    __syncthreads();

    const int w    = tid >> 6;
    const int wm   = w >> 1, wn = w & 1;
    const int row  = mt * 32 + wm * 16 + (lane & 15);
    const int koff = (lane >> 4) * 8;
    const float* xp = x + row * DIM + koff;
    const unsigned short* bp1 = &Bt[16 * wn + (lane & 15)][koff];
    const unsigned short* bp2 = &Bt[32 + 16 * wn + (lane & 15)][koff];

    f32x4 acc1 = {0.f, 0.f, 0.f, 0.f};
    f32x4 acc2 = {0.f, 0.f, 0.f, 0.f};
    #pragma unroll
    for (int kk = 0; kk < 8; ++kk) {     // K = 8 x 32
        const float4 xa = *(const float4*)(xp + kk * 32);
        const float4 xb = *(const float4*)(xp + kk * 32 + 4);
        u32x4 a;
        a.x = cvtpk(xa.x, xa.y);
        a.y = cvtpk(xa.z, xa.w);
        a.z = cvtpk(xb.x, xb.y);
        a.w = cvtpk(xb.z, xb.w);
        const u32x4 b1 = *(const u32x4*)(bp1 + kk * 32);
        const u32x4 b2 = *(const u32x4*)(bp2 + kk * 32);
        acc1 = mfma16(a, b1, acc1);
        acc2 = mfma16(a, b2, acc2);
    }

    const int rowbase = mt * 32 + wm * 16 + (lane >> 4) * 4;   // %4 == 0
    if (role < 8) {
        const int n = 32 * role + 16 * wn + (lane & 15);
        u32x4 st;
        st.x = pack_bg(acc1[0], acc2[0]);    // row rowbase+0
        st.y = pack_bg(acc1[1], acc2[1]);    // row rowbase+1
        st.z = pack_bg(acc1[2], acc2[2]);    // row rowbase+2
        st.w = pack_bg(acc1[3], acc2[3]);    // row rowbase+3
        betgam4[(rowbase >> 2) * NST + n] = st;
    } else {
        const int c1 = 16 * wn + (lane & 15);
        #pragma unroll
        for (int r = 0; r < 4; ++r) {
            draw[(rowbase + r) * DTSZ + c1]      = acc1[r];
            draw[(rowbase + r) * DTSZ + 32 + c1] = acc2[r];
        }
    }
}

// ---------------- scan1p: R7 skeleton (measured 41.0us) with the part[]
// reduce double-buffered: window-group g writes part[g&1]; ONE barrier per
// reduce (the trailing WAR barrier is gone — 16 fewer barriers).
// Safety: per thread the order is ... writes(g)->barrier->reduce(g&1)->
// writes(g+1, other buf)->barrier->reduce->writes(g+2, same buf as g).
// Any thread's writes(g+2) are AFTER that barrier; any thread's reduce(g)
// is BEFORE it -> no WAR race across threads.
__global__ __launch_bounds__(256, 2) void scan1p(
    const float* __restrict__ x,            // [NROWS, DIM]
    const float* __restrict__ alpha_log,    // [DIM, NST]
    const float* __restrict__ delta,        // [DIM]
    const u32x4* __restrict__ betgam4,      // [NROWS/4, NST] row-quads
    const float* __restrict__ draw,         // [NROWS, DTSZ]
    const float* __restrict__ W_dt,         // [DTSZ, DIM]
    const float* __restrict__ b_dt,         // [DIM]
    float* __restrict__ out)                // [NROWS, DIM]
{
    __shared__ float part[2][32][NST];      // 64 KB double-buffered
    __shared__ float dts[LSEQ], dxs[LSEQ], xcol[LSEQ];   // 3 x 2 KB
    __shared__ float wdt[DTSZ];             // 256 B
    const int n = threadIdx.x;
    // XCD swizzle (R10-verified): XCDs 0-3 -> b=0, 4-7 -> b=1.
    const int xcd  = blockIdx.x & 7;
    const int slot = blockIdx.x >> 3;       // 0..63
    const int b = xcd >> 2;
    const int d = slot * 4 + (xcd & 3);
    const int rb  = b * LSEQ;
    const int rbq = rb >> 2;                // quad-row base (= b*128)

    if (n < DTSZ) wdt[n] = W_dt[n * DIM + d];
    #pragma unroll
    for (int it = 0; it < 2; ++it) {
        const int l = n + it * 256;
        xcol[l] = x[(rb + l) * DIM + d];
    }
    const float aln = -__expf(alpha_log[d * NST + n]) * LOG2E;
    const float dv  = delta[d];
    const float bdv = b_dt[d];

    // Issue the 6-window betgam prefetch NOW (12 dwordx4 loads); they stay
    // in flight through the dt prologue below.
    u32x4 bg[8][2];                         // 8-slot rotation of row-quads
    #pragma unroll
    for (int pw = 0; pw < 6; ++pw) {
        #pragma unroll
        for (int h = 0; h < 2; ++h)
            bg[pw][h] = betgam4[(rbq + pw * 2 + h) * NST + n];
    }

    barrier_lds_only();                     // wdt/xcol visible; vmcnt untouched

    // Fused dt GEMM: dts[l] = softplus(draw[rb+l,:] . wdt + b_dt[d])
    #pragma unroll
    for (int it = 0; it < 2; ++it) {
        const int l = n + it * 256;
        const float4* dr = (const float4*)&draw[(rb + l) * DTSZ];
        float acc = bdv;
        #pragma unroll
        for (int c = 0; c < 16; ++c) {
            const float4 v  = dr[c];
            const float4 wv = *(const float4*)&wdt[c * 4];
            acc = fmaf(v.x, wv.x, acc);
            acc = fmaf(v.y, wv.y, acc);
            acc = fmaf(v.z, wv.z, acc);
            acc = fmaf(v.w, wv.w, acc);
        }
        const float sp = softplusf(acc);
        dts[l] = sp;
        dxs[l] = sp * xcol[l];
    }
    __syncthreads();                        // dts/dxs ready

    float s = 0.f;
    #pragma unroll 8
    for (int w = 0; w < 64; ++w) {
        const int cur = w & 7;              // static under unroll-8
        const int pf  = (w + 6) & 7;
        const int bufsel = (w >> 2) & 1;    // static: group double-buffer
        if (w + 6 < 64) {                   // issue window w+6 while computing w
            bg[pf][0] = betgam4[(rbq + (w + 6) * 2)     * NST + n];
            bg[pf][1] = betgam4[(rbq + (w + 6) * 2 + 1) * NST + n];
        }
        float4 dta = *(const float4*)&dts[w * 8];
        float4 dtb = *(const float4*)&dts[w * 8 + 4];
        float4 dxa = *(const float4*)&dxs[w * 8];
        float4 dxb = *(const float4*)&dxs[w * 8 + 4];
        const float dtw[8] = {dta.x, dta.y, dta.z, dta.w, dtb.x, dtb.y, dtb.z, dtb.w};
        const float dxw[8] = {dxa.x, dxa.y, dxa.z, dxa.w, dxb.x, dxb.y, dxb.z, dxb.w};

        const int prow = (w & 3) * 8;
        #pragma unroll
        for (int t = 0; t < 8; ++t) {       // t static: bg[cur][t>>2][t&3] const-indexed
            const unsigned u = bg[cur][t >> 2][t & 3];
            const float be = __uint_as_float(u << 16);
            const float ga = __uint_as_float(u & 0xffff0000u);
            float a = fexp2(dtw[t] * aln);
            s = fmaf(a, s, dxw[t] * be);
            part[bufsel][prow + t][n] = s * ga;   // 2-way bank alias: free
        }

        if ((w & 3) == 3) {                 // every 32 steps: reduce 32 rows x 256
            barrier_lds_only();             // writes(group) complete; also the
                                            // WAR fence for group g+2 (see top)
            const int trow = n >> 3, seg = n & 7;
            float sum = 0.f;
            #pragma unroll
            for (int k = 0; k < 32; ++k)
                sum += part[bufsel][trow][seg * 32 + ((k + n) & 31)];  // 0-conflict
            sum += __shfl_xor(sum, 1);
            sum += __shfl_xor(sum, 2);
            sum += __shfl_xor(sum, 4);
            if (seg == 0) {
                const int l = (w >> 2) * 32 + trow;
                out[(rb + l) * DIM + d] = sum + xcol[l] * dv;
            }
            // no trailing barrier: next group writes the OTHER buffer
        }
    }
}

extern "C" void kernel_launch(void* const* d_in, const int* in_sizes, int n_in,
                              void* d_out, int out_size, void* d_ws, size_t ws_size,
                              hipStream_t stream) {
    const float* x         = (const float*)d_in[0];
    const float* W_in      = (const float*)d_in[1];
    const float* W_dt      = (const float*)d_in[2];
    const float* b_dt      = (const float*)d_in[3];
    const float* alpha_log = (const float*)d_in[4];
    const float* delta     = (const float*)d_in[5];
    float* out = (float*)d_out;

    // Workspace: betgam4 1MB | draw 256KB
    u32x4* betgam4 = (u32x4*)d_ws;
    float* draw    = (float*)(betgam4 + (NROWS / 4) * NST);

    proj_mfma<<<32 * 9, 256, 0, stream>>>(x, W_in, betgam4, draw);
    scan1p<<<BAT * DIM, 256, 0, stream>>>(x, alpha_log, delta, betgam4,
                                          draw, W_dt, b_dt, out);
}